// Round 1
// baseline (308.245 us; speedup 1.0000x reference)
//
#include <hip/hip_runtime.h>
#include <math.h>

#define DD 128          // embed dim
#define DEG 16          // neighbors
#define TILE_M 64
#define EPSV 1e-5f

// ---------------- msg = (x*mask) @ W, then *mask ; both relations ----------------
__global__ __launch_bounds__(256) void msg_mm(
    const float* __restrict__ x,
    const float* __restrict__ Wp, const float* __restrict__ Wn,
    const float* __restrict__ mask,
    float* __restrict__ msgP, float* __restrict__ msgN, int n)
{
    __shared__ float As[TILE_M][DD];   // 32 KB
    const int rel = blockIdx.y;
    const float* __restrict__ W = rel ? Wn : Wp;
    float* __restrict__ out = rel ? msgN : msgP;
    const int row0 = blockIdx.x * TILE_M;

    // stage A tile: 64 rows x 128 cols = 2048 float4, 256 threads -> 8 each
    #pragma unroll
    for (int i = 0; i < 8; ++i) {
        int f4 = threadIdx.x + i * 256;      // 0..2047
        int r  = f4 >> 5;                    // 32 float4 per row
        int c4 = f4 & 31;
        int row = row0 + r;
        float4 v = make_float4(0.f, 0.f, 0.f, 0.f);
        if (row < n) {
            v = ((const float4*)(x + (size_t)row * DD))[c4];
            float m = mask[row];
            v.x *= m; v.y *= m; v.z *= m; v.w *= m;
        }
        ((float4*)As[r])[c4] = v;
    }
    __syncthreads();

    const int colg = threadIdx.x & 31;   // col = colg*4
    const int rgrp = threadIdx.x >> 5;   // rows rgrp*8 .. +7

    float4 acc[8];
    #pragma unroll
    for (int r = 0; r < 8; ++r) acc[r] = make_float4(0.f, 0.f, 0.f, 0.f);

    for (int k = 0; k < DD; k += 4) {
        float4 w0 = ((const float4*)(W + (size_t)(k + 0) * DD))[colg];
        float4 w1 = ((const float4*)(W + (size_t)(k + 1) * DD))[colg];
        float4 w2 = ((const float4*)(W + (size_t)(k + 2) * DD))[colg];
        float4 w3 = ((const float4*)(W + (size_t)(k + 3) * DD))[colg];
        #pragma unroll
        for (int r = 0; r < 8; ++r) {
            int rr = rgrp * 8 + r;
            float4 a = ((const float4*)(As[rr]))[k >> 2];
            acc[r].x += a.x * w0.x + a.y * w1.x + a.z * w2.x + a.w * w3.x;
            acc[r].y += a.x * w0.y + a.y * w1.y + a.z * w2.y + a.w * w3.y;
            acc[r].z += a.x * w0.z + a.y * w1.z + a.z * w2.z + a.w * w3.z;
            acc[r].w += a.x * w0.w + a.y * w1.w + a.z * w2.w + a.w * w3.w;
        }
    }

    #pragma unroll
    for (int r = 0; r < 8; ++r) {
        int row = row0 + rgrp * 8 + r;
        if (row < n) {
            float m = mask[row];
            float4 v = acc[r];
            v.x *= m; v.y *= m; v.z *= m; v.w *= m;
            ((float4*)(out + (size_t)row * DD))[colg] = v;
        }
    }
}

// ---- combined = sum_j |w| * msg{P|N}[adj]; exp-map + relu (+ optional log-map) ----
__global__ __launch_bounds__(256) void agg(
    const int*   __restrict__ adj, const float* __restrict__ wgt,
    const float* __restrict__ msgP, const float* __restrict__ msgN,
    const float* __restrict__ mask, float* __restrict__ out,
    int n, int apply_logmap)
{
    const int lane = threadIdx.x & 31;                 // 32 lanes per node
    const int node = blockIdx.x * 8 + (threadIdx.x >> 5);
    if (node >= n) return;

    const int*   __restrict__ arow = adj + (size_t)node * DEG;
    const float* __restrict__ wrow = wgt + (size_t)node * DEG;

    float4 acc = make_float4(0.f, 0.f, 0.f, 0.f);
    #pragma unroll
    for (int j = 0; j < DEG; ++j) {
        float w  = wrow[j];            // broadcast load (same addr across 32 lanes)
        int  idx = arow[j];
        const float* __restrict__ base = (w > 0.f) ? msgP : msgN;  // branchless
        float aw = fabsf(w);
        float4 v = ((const float4*)(base + (size_t)idx * DD))[lane];
        acc.x += aw * v.x; acc.y += aw * v.y; acc.z += aw * v.z; acc.w += aw * v.w;
    }

    const float m = mask[node];
    acc.x *= m; acc.y *= m; acc.z *= m; acc.w *= m;    // combined * mask

    // exp_map_zero: scale = tanh(max(||c||, eps)) / max(||c||, eps)
    float s = acc.x*acc.x + acc.y*acc.y + acc.z*acc.z + acc.w*acc.w;
    #pragma unroll
    for (int off = 1; off < 32; off <<= 1) s += __shfl_xor(s, off, 32);
    float nrm = sqrtf(s);
    float nc  = fmaxf(nrm, EPSV);
    float sc  = tanhf(nc) / nc;

    float4 xv;
    xv.x = fmaxf(acc.x * sc * m, 0.f) * m;             // expmap*mask, relu, *mask
    xv.y = fmaxf(acc.y * sc * m, 0.f) * m;
    xv.z = fmaxf(acc.z * sc * m, 0.f) * m;
    xv.w = fmaxf(acc.w * sc * m, 0.f) * m;

    if (apply_logmap) {
        // log_map_zero for next layer's input (its *mask happens in msg_mm's A load)
        float s2 = xv.x*xv.x + xv.y*xv.y + xv.z*xv.z + xv.w*xv.w;
        #pragma unroll
        for (int off = 1; off < 32; off <<= 1) s2 += __shfl_xor(s2, off, 32);
        float n2  = sqrtf(s2);
        float nc2 = fminf(fmaxf(n2, EPSV), 1.f - EPSV);
        float sc2 = atanhf(nc2) / nc2;
        xv.x *= sc2; xv.y *= sc2; xv.z *= sc2; xv.w *= sc2;
    }
    ((float4*)(out + (size_t)node * DD))[lane] = xv;
}

extern "C" void kernel_launch(void* const* d_in, const int* in_sizes, int n_in,
                              void* d_out, int out_size, void* d_ws, size_t ws_size,
                              hipStream_t stream)
{
    const float* node_repr = (const float*)d_in[0];
    const int*   adj       = (const int*)  d_in[1];
    const float* weight    = (const float*)d_in[2];
    const float* mask      = (const float*)d_in[3];
    const float* W_pos     = (const float*)d_in[4];   // [L,128,128]
    const float* W_neg     = (const float*)d_in[5];

    const int n = in_sizes[0] / DD;                   // 50000

    float* msgP = (float*)d_ws;
    float* msgN = msgP + (size_t)n * DD;
    float* xl   = msgN + (size_t)n * DD;

    dim3 mmGrid((n + TILE_M - 1) / TILE_M, 2);
    dim3 aggGrid((n + 7) / 8);

    // layer 0
    msg_mm<<<mmGrid, 256, 0, stream>>>(node_repr, W_pos, W_neg, mask, msgP, msgN, n);
    agg   <<<aggGrid, 256, 0, stream>>>(adj, weight, msgP, msgN, mask, xl, n, 1);
    // layer 1
    msg_mm<<<mmGrid, 256, 0, stream>>>(xl, W_pos + DD * DD, W_neg + DD * DD, mask,
                                       msgP, msgN, n);
    agg   <<<aggGrid, 256, 0, stream>>>(adj, weight, msgP, msgN, mask,
                                        (float*)d_out, n, 0);
}

// Round 2
// 306.872 us; speedup vs baseline: 1.0045x; 1.0045x over previous
//
#include <hip/hip_runtime.h>
#include <math.h>

#define DD 128          // embed dim
#define DEG 16          // neighbors
#define TM 64           // node tile per block
#define EPSV 1e-5f

// One GNN layer, fully fused:
//   aggP[i] = sum_j max(w_ij,0)*mask[a_ij]^2 * src[a_ij]     (gather-aggregate)
//   aggN[i] = sum_j max(-w_ij,0)*mask[a_ij]^2 * src[a_ij]
//   c[i]    = (aggP[i] @ Wp + aggN[i] @ Wn) * mask[i]        (matmul, fused epilogue)
//   x       = relu(expmap(c)*m)*m ; optionally store logmap(x) for next layer
// Valid because matmul commutes with the weighted sum, and the reference's
// per-source masking (x*mask before @W, msg*mask after) folds to mask[src]^2.
__global__ __launch_bounds__(256) void fused_layer(
    const float* __restrict__ src,
    const int*   __restrict__ adj, const float* __restrict__ wgt,
    const float* __restrict__ mask,
    const float* __restrict__ Wp, const float* __restrict__ Wn,
    float* __restrict__ dst, int n, int apply_logmap)
{
    __shared__ float aggP[TM][DD];   // 32 KB
    __shared__ float aggN[TM][DD];   // 32 KB

    const int row0 = blockIdx.x * TM;
    const int lane = threadIdx.x & 31;   // 32 lanes cover the 128 cols (float4)
    const int hw   = threadIdx.x >> 5;   // half-wave id 0..7

    // ---- phase 1: gather-aggregate, 8 nodes per half-wave ----
    for (int i = 0; i < 8; ++i) {
        const int r    = hw * 8 + i;
        const int node = row0 + r;
        float4 aP = make_float4(0.f, 0.f, 0.f, 0.f);
        float4 aN = make_float4(0.f, 0.f, 0.f, 0.f);
        if (node < n) {
            const int*   __restrict__ arow = adj + (size_t)node * DEG;
            const float* __restrict__ wrow = wgt + (size_t)node * DEG;
            #pragma unroll
            for (int j = 0; j < DEG; ++j) {
                float w   = wrow[j];          // broadcast loads across half-wave
                int   idx = arow[j];
                float m   = mask[idx];
                float m2  = m * m;
                float wp  = fmaxf(w, 0.f)  * m2;
                float wn  = fmaxf(-w, 0.f) * m2;
                float4 v  = ((const float4*)(src + (size_t)idx * DD))[lane];
                aP.x += wp * v.x; aP.y += wp * v.y; aP.z += wp * v.z; aP.w += wp * v.w;
                aN.x += wn * v.x; aN.y += wn * v.y; aN.z += wn * v.z; aN.w += wn * v.w;
            }
        }
        ((float4*)aggP[r])[lane] = aP;
        ((float4*)aggN[r])[lane] = aN;
    }
    __syncthreads();

    // ---- phase 2: combined = aggP@Wp + aggN@Wn (8 rows x 4 cols per thread) ----
    const int colg = lane;               // output cols colg*4 .. +3
    float4 acc[8];
    #pragma unroll
    for (int r = 0; r < 8; ++r) acc[r] = make_float4(0.f, 0.f, 0.f, 0.f);

    for (int k = 0; k < DD; k += 4) {
        float4 p0 = ((const float4*)(Wp + (size_t)(k + 0) * DD))[colg];
        float4 p1 = ((const float4*)(Wp + (size_t)(k + 1) * DD))[colg];
        float4 p2 = ((const float4*)(Wp + (size_t)(k + 2) * DD))[colg];
        float4 p3 = ((const float4*)(Wp + (size_t)(k + 3) * DD))[colg];
        float4 q0 = ((const float4*)(Wn + (size_t)(k + 0) * DD))[colg];
        float4 q1 = ((const float4*)(Wn + (size_t)(k + 1) * DD))[colg];
        float4 q2 = ((const float4*)(Wn + (size_t)(k + 2) * DD))[colg];
        float4 q3 = ((const float4*)(Wn + (size_t)(k + 3) * DD))[colg];
        #pragma unroll
        for (int r = 0; r < 8; ++r) {
            const int rr = hw * 8 + r;
            float4 a = ((const float4*)(aggP[rr]))[k >> 2];   // broadcast LDS read
            float4 b = ((const float4*)(aggN[rr]))[k >> 2];
            acc[r].x += a.x*p0.x + a.y*p1.x + a.z*p2.x + a.w*p3.x
                      + b.x*q0.x + b.y*q1.x + b.z*q2.x + b.w*q3.x;
            acc[r].y += a.x*p0.y + a.y*p1.y + a.z*p2.y + a.w*p3.y
                      + b.x*q0.y + b.y*q1.y + b.z*q2.y + b.w*q3.y;
            acc[r].z += a.x*p0.z + a.y*p1.z + a.z*p2.z + a.w*p3.z
                      + b.x*q0.z + b.y*q1.z + b.z*q2.z + b.w*q3.z;
            acc[r].w += a.x*p0.w + a.y*p1.w + a.z*p2.w + a.w*p3.w
                      + b.x*q0.w + b.y*q1.w + b.z*q2.w + b.w*q3.w;
        }
    }

    // ---- phase 3: epilogue per row (norm via half-wave shuffle) ----
    #pragma unroll
    for (int r = 0; r < 8; ++r) {
        const int row = row0 + hw * 8 + r;
        if (row >= n) continue;
        const float m = mask[row];
        float4 c = acc[r];
        c.x *= m; c.y *= m; c.z *= m; c.w *= m;          // combined * mask

        float s = c.x*c.x + c.y*c.y + c.z*c.z + c.w*c.w; // exp_map_zero
        #pragma unroll
        for (int off = 1; off < 32; off <<= 1) s += __shfl_xor(s, off, 32);
        float nc = fmaxf(sqrtf(s), EPSV);
        float sc = tanhf(nc) / nc;

        float4 xv;
        xv.x = fmaxf(c.x * sc * m, 0.f) * m;             // expmap*m, relu, *m
        xv.y = fmaxf(c.y * sc * m, 0.f) * m;
        xv.z = fmaxf(c.z * sc * m, 0.f) * m;
        xv.w = fmaxf(c.w * sc * m, 0.f) * m;

        if (apply_logmap) {                               // next layer's logmap
            float s2 = xv.x*xv.x + xv.y*xv.y + xv.z*xv.z + xv.w*xv.w;
            #pragma unroll
            for (int off = 1; off < 32; off <<= 1) s2 += __shfl_xor(s2, off, 32);
            float nc2 = fminf(fmaxf(sqrtf(s2), EPSV), 1.f - EPSV);
            float sc2 = atanhf(nc2) / nc2;
            xv.x *= sc2; xv.y *= sc2; xv.z *= sc2; xv.w *= sc2;
        }
        ((float4*)(dst + (size_t)row * DD))[lane] = xv;
    }
}

extern "C" void kernel_launch(void* const* d_in, const int* in_sizes, int n_in,
                              void* d_out, int out_size, void* d_ws, size_t ws_size,
                              hipStream_t stream)
{
    const float* node_repr = (const float*)d_in[0];
    const int*   adj       = (const int*)  d_in[1];
    const float* weight    = (const float*)d_in[2];
    const float* mask      = (const float*)d_in[3];
    const float* W_pos     = (const float*)d_in[4];   // [L,128,128]
    const float* W_neg     = (const float*)d_in[5];

    const int n = in_sizes[0] / DD;                   // 50000
    float* y0 = (float*)d_ws;                          // logmap(layer0 out)

    dim3 grid((n + TM - 1) / TM);

    // layer 0: src = node_repr (raw; mask^2 folded into gather weights)
    fused_layer<<<grid, 256, 0, stream>>>(node_repr, adj, weight, mask,
                                          W_pos, W_neg, y0, n, 1);
    // layer 1
    fused_layer<<<grid, 256, 0, stream>>>(y0, adj, weight, mask,
                                          W_pos + DD * DD, W_neg + DD * DD,
                                          (float*)d_out, n, 0);
}

// Round 3
// 299.412 us; speedup vs baseline: 1.0295x; 1.0249x over previous
//
#include <hip/hip_runtime.h>
#include <math.h>

#define DD 128          // embed dim
#define DEG 16          // neighbors
#define TM 32           // node tile per block (32KB LDS -> 5 blocks/CU)
#define EPSV 1e-5f

// One GNN layer, fully fused (agg-then-matmul; matmul commutes with weighted sum):
//   aggP[i] = sum_j max(w_ij,0)*mask[a_ij]^2 * src[a_ij]
//   aggN[i] = sum_j max(-w_ij,0)*mask[a_ij]^2 * src[a_ij]
//   c[i]    = (aggP[i] @ Wp + aggN[i] @ Wn) * mask[i]
//   x       = relu(expmap(c)*m)*m ; optionally store logmap(x) for next layer
__global__ __launch_bounds__(256, 5) void fused_layer(
    const float* __restrict__ src,
    const int*   __restrict__ adj, const float* __restrict__ wgt,
    const float* __restrict__ mask,
    const float* __restrict__ Wp, const float* __restrict__ Wn,
    float* __restrict__ dst, int n, int apply_logmap)
{
    __shared__ float aggP[TM][DD];   // 16 KB
    __shared__ float aggN[TM][DD];   // 16 KB

    const int row0 = blockIdx.x * TM;
    const int lane = threadIdx.x & 31;   // 32 lanes cover the 128 cols (float4)
    const int hw   = threadIdx.x >> 5;   // half-wave id 0..7

    // ---- phase 1: gather-aggregate, 4 nodes per half-wave ----
    #pragma unroll
    for (int i = 0; i < 4; ++i) {
        const int r    = hw * 4 + i;
        const int node = row0 + r;
        float4 aP = make_float4(0.f, 0.f, 0.f, 0.f);
        float4 aN = make_float4(0.f, 0.f, 0.f, 0.f);
        if (node < n) {
            const int*   __restrict__ arow = adj + (size_t)node * DEG;
            const float* __restrict__ wrow = wgt + (size_t)node * DEG;
            #pragma unroll
            for (int j = 0; j < DEG; ++j) {
                float w   = wrow[j];          // broadcast loads across half-wave
                int   idx = arow[j];
                float m   = mask[idx];
                float m2  = m * m;
                float wp  = fmaxf(w, 0.f)  * m2;
                float wn  = fmaxf(-w, 0.f) * m2;
                float4 v  = ((const float4*)(src + (size_t)idx * DD))[lane];
                aP.x += wp * v.x; aP.y += wp * v.y; aP.z += wp * v.z; aP.w += wp * v.w;
                aN.x += wn * v.x; aN.y += wn * v.y; aN.z += wn * v.z; aN.w += wn * v.w;
            }
        }
        ((float4*)aggP[r])[lane] = aP;
        ((float4*)aggN[r])[lane] = aN;
    }
    __syncthreads();

    // ---- phase 2: combined = aggP@Wp + aggN@Wn (4 rows x 4 cols per thread) ----
    const int colg = lane;               // output cols colg*4 .. +3
    float4 acc[4];
    #pragma unroll
    for (int r = 0; r < 4; ++r) acc[r] = make_float4(0.f, 0.f, 0.f, 0.f);

    for (int k = 0; k < DD; k += 4) {
        float4 p0 = ((const float4*)(Wp + (size_t)(k + 0) * DD))[colg];
        float4 p1 = ((const float4*)(Wp + (size_t)(k + 1) * DD))[colg];
        float4 p2 = ((const float4*)(Wp + (size_t)(k + 2) * DD))[colg];
        float4 p3 = ((const float4*)(Wp + (size_t)(k + 3) * DD))[colg];
        float4 q0 = ((const float4*)(Wn + (size_t)(k + 0) * DD))[colg];
        float4 q1 = ((const float4*)(Wn + (size_t)(k + 1) * DD))[colg];
        float4 q2 = ((const float4*)(Wn + (size_t)(k + 2) * DD))[colg];
        float4 q3 = ((const float4*)(Wn + (size_t)(k + 3) * DD))[colg];
        #pragma unroll
        for (int r = 0; r < 4; ++r) {
            const int rr = hw * 4 + r;
            float4 a = ((const float4*)(aggP[rr]))[k >> 2];   // broadcast LDS read
            float4 b = ((const float4*)(aggN[rr]))[k >> 2];
            acc[r].x += a.x*p0.x + a.y*p1.x + a.z*p2.x + a.w*p3.x
                      + b.x*q0.x + b.y*q1.x + b.z*q2.x + b.w*q3.x;
            acc[r].y += a.x*p0.y + a.y*p1.y + a.z*p2.y + a.w*p3.y
                      + b.x*q0.y + b.y*q1.y + b.z*q2.y + b.w*q3.y;
            acc[r].z += a.x*p0.z + a.y*p1.z + a.z*p2.z + a.w*p3.z
                      + b.x*q0.z + b.y*q1.z + b.z*q2.z + b.w*q3.z;
            acc[r].w += a.x*p0.w + a.y*p1.w + a.z*p2.w + a.w*p3.w
                      + b.x*q0.w + b.y*q1.w + b.z*q2.w + b.w*q3.w;
        }
    }

    // ---- phase 3: epilogue per row (norm via half-wave shuffle) ----
    #pragma unroll
    for (int r = 0; r < 4; ++r) {
        const int row = row0 + hw * 4 + r;
        if (row >= n) continue;
        const float m = mask[row];
        float4 c = acc[r];
        c.x *= m; c.y *= m; c.z *= m; c.w *= m;          // combined * mask

        float s = c.x*c.x + c.y*c.y + c.z*c.z + c.w*c.w; // exp_map_zero
        #pragma unroll
        for (int off = 1; off < 32; off <<= 1) s += __shfl_xor(s, off, 32);
        float nc = fmaxf(sqrtf(s), EPSV);
        float sc = tanhf(nc) / nc;

        float4 xv;
        xv.x = fmaxf(c.x * sc * m, 0.f) * m;             // expmap*m, relu, *m
        xv.y = fmaxf(c.y * sc * m, 0.f) * m;
        xv.z = fmaxf(c.z * sc * m, 0.f) * m;
        xv.w = fmaxf(c.w * sc * m, 0.f) * m;

        if (apply_logmap) {                               // next layer's logmap
            float s2 = xv.x*xv.x + xv.y*xv.y + xv.z*xv.z + xv.w*xv.w;
            #pragma unroll
            for (int off = 1; off < 32; off <<= 1) s2 += __shfl_xor(s2, off, 32);
            float nc2 = fminf(fmaxf(sqrtf(s2), EPSV), 1.f - EPSV);
            float sc2 = atanhf(nc2) / nc2;
            xv.x *= sc2; xv.y *= sc2; xv.z *= sc2; xv.w *= sc2;
        }
        ((float4*)(dst + (size_t)row * DD))[lane] = xv;
    }
}

extern "C" void kernel_launch(void* const* d_in, const int* in_sizes, int n_in,
                              void* d_out, int out_size, void* d_ws, size_t ws_size,
                              hipStream_t stream)
{
    const float* node_repr = (const float*)d_in[0];
    const int*   adj       = (const int*)  d_in[1];
    const float* weight    = (const float*)d_in[2];
    const float* mask      = (const float*)d_in[3];
    const float* W_pos     = (const float*)d_in[4];   // [L,128,128]
    const float* W_neg     = (const float*)d_in[5];

    const int n = in_sizes[0] / DD;                   // 50000
    float* y0 = (float*)d_ws;                          // logmap(layer0 out)

    dim3 grid((n + TM - 1) / TM);

    // layer 0: src = node_repr (raw; mask^2 folded into gather weights)
    fused_layer<<<grid, 256, 0, stream>>>(node_repr, adj, weight, mask,
                                          W_pos, W_neg, y0, n, 1);
    // layer 1
    fused_layer<<<grid, 256, 0, stream>>>(y0, adj, weight, mask,
                                          W_pos + DD * DD, W_neg + DD * DD,
                                          (float*)d_out, n, 0);
}

// Round 4
// 210.462 us; speedup vs baseline: 1.4646x; 1.4226x over previous
//
#include <hip/hip_runtime.h>
#include <math.h>

#define DD 128          // embed dim
#define DEG 16          // neighbors
#define TM 32           // node tile per block (2 waves x 16 rows)
#define LDST 136        // LDS row stride in f16 (128 + 8 pad -> 2-way banks, free)
#define EPSV 1e-5f

typedef _Float16 half4_t __attribute__((ext_vector_type(4)));
typedef _Float16 half8_t __attribute__((ext_vector_type(8)));
typedef float    f32x4   __attribute__((ext_vector_type(4)));

// ---- prep: fp32 node table -> f16 copy (halves gather bytes) ----
__global__ void prep_x(const float* __restrict__ x, _Float16* __restrict__ x16, int n4)
{
    int i = blockIdx.x * blockDim.x + threadIdx.x;
    if (i >= n4) return;
    float4 v = ((const float4*)x)[i];
    half4_t h;
    h[0] = (_Float16)v.x; h[1] = (_Float16)v.y; h[2] = (_Float16)v.z; h[3] = (_Float16)v.w;
    ((half4_t*)x16)[i] = h;
}

// ---- prep: W [L][128][128] fp32 -> f16 TRANSPOSED WT[l][rel][n][k] ----
// (transposed so MFMA B-fragments read contiguous 16B along k)
__global__ void prep_w(const float* __restrict__ Wp, const float* __restrict__ Wn,
                       _Float16* __restrict__ WT)
{
    const int l = blockIdx.x >> 1, rel = blockIdx.x & 1;
    const float* __restrict__ src = (rel ? Wn : Wp) + (size_t)l * DD * DD;
    _Float16* __restrict__ dst = WT + (size_t)blockIdx.x * DD * DD;
    for (int o = threadIdx.x; o < DD * DD; o += blockDim.x) {
        int nn = o >> 7, kk = o & 127;
        dst[o] = (_Float16)src[kk * DD + nn];
    }
}

// ---- one fused GNN layer: gather-agg (fp32) -> f16 LDS -> MFMA -> epilogue ----
__global__ __launch_bounds__(128, 4) void fused_layer(
    const _Float16* __restrict__ src16,
    const int*   __restrict__ adj, const float* __restrict__ wgt,
    const float* __restrict__ mask,
    const _Float16* __restrict__ WTp, const _Float16* __restrict__ WTn,
    float* __restrict__ dst_f32, _Float16* __restrict__ dst_f16,
    int n, int apply_logmap)
{
    __shared__ __align__(16) _Float16 aggP[TM][LDST];   // 8.5 KB
    __shared__ __align__(16) _Float16 aggN[TM][LDST];   // 8.5 KB

    const int row0   = blockIdx.x * TM;
    const int tid    = threadIdx.x;
    const int lane32 = tid & 31;     // 32 lanes cover 128 cols (4 f16 each)
    const int hw     = tid >> 5;     // half-wave 0..3

    // ---- phase 1: gather-aggregate (fp32 accum), 8 nodes per half-wave ----
    #pragma unroll
    for (int i = 0; i < 8; ++i) {
        const int r    = hw * 8 + i;
        const int node = row0 + r;
        f32x4 aP = {0.f, 0.f, 0.f, 0.f};
        f32x4 aN = {0.f, 0.f, 0.f, 0.f};
        if (node < n) {
            const int*   __restrict__ arow = adj + (size_t)node * DEG;
            const float* __restrict__ wrow = wgt + (size_t)node * DEG;
            #pragma unroll
            for (int j = 0; j < DEG; ++j) {
                float w   = wrow[j];            // uniform across half-wave
                int   idx = arow[j];
                float m   = mask[idx];
                float m2  = m * m;              // mask[src]^2 (pre- and post-matmul mask)
                float wp  = fmaxf(w, 0.f)  * m2;
                float wn  = fmaxf(-w, 0.f) * m2;
                half4_t v = *(const half4_t*)(src16 + (size_t)idx * DD + lane32 * 4);
                float v0 = (float)v[0], v1 = (float)v[1], v2 = (float)v[2], v3 = (float)v[3];
                aP[0] += wp * v0; aP[1] += wp * v1; aP[2] += wp * v2; aP[3] += wp * v3;
                aN[0] += wn * v0; aN[1] += wn * v1; aN[2] += wn * v2; aN[3] += wn * v3;
            }
        }
        half4_t hP, hN;
        hP[0] = (_Float16)aP[0]; hP[1] = (_Float16)aP[1];
        hP[2] = (_Float16)aP[2]; hP[3] = (_Float16)aP[3];
        hN[0] = (_Float16)aN[0]; hN[1] = (_Float16)aN[1];
        hN[2] = (_Float16)aN[2]; hN[3] = (_Float16)aN[3];
        *(half4_t*)&aggP[r][lane32 * 4] = hP;
        *(half4_t*)&aggN[r][lane32 * 4] = hN;
    }
    __syncthreads();

    // ---- phase 2: C[32x128] = aggP@Wp + aggN@Wn via mfma_f32_16x16x32_f16 ----
    const int wv   = tid >> 6;       // wave 0/1 -> rows 16w..16w+15
    const int l64  = tid & 63;
    const int l15  = l64 & 15;
    const int quad = l64 >> 4;

    half8_t aPf[4], aNf[4];          // A-frags: A[m=l15][k=kb*32+quad*8+j]
    #pragma unroll
    for (int kb = 0; kb < 4; ++kb) {
        aPf[kb] = *(const half8_t*)&aggP[16 * wv + l15][kb * 32 + quad * 8];
        aNf[kb] = *(const half8_t*)&aggN[16 * wv + l15][kb * 32 + quad * 8];
    }

    f32x4 acc[8];
    #pragma unroll
    for (int nb = 0; nb < 8; ++nb) acc[nb] = (f32x4){0.f, 0.f, 0.f, 0.f};

    #pragma unroll
    for (int nb = 0; nb < 8; ++nb) {
        const _Float16* bp = WTp + (size_t)(nb * 16 + l15) * DD + quad * 8;
        const _Float16* bn = WTn + (size_t)(nb * 16 + l15) * DD + quad * 8;
        #pragma unroll
        for (int kb = 0; kb < 4; ++kb) {
            half8_t bP = *(const half8_t*)(bp + kb * 32);  // B[k][n], contiguous in k
            half8_t bN = *(const half8_t*)(bn + kb * 32);
            acc[nb] = __builtin_amdgcn_mfma_f32_16x16x32_f16(aPf[kb], bP, acc[nb], 0, 0, 0);
            acc[nb] = __builtin_amdgcn_mfma_f32_16x16x32_f16(aNf[kb], bN, acc[nb], 0, 0, 0);
        }
    }

    // ---- phase 3: epilogue. C/D: row=quad*4+r, col=nb*16+l15 ----
    #pragma unroll
    for (int r = 0; r < 4; ++r) {
        const int row = row0 + 16 * wv + quad * 4 + r;
        const float m = (row < n) ? mask[row] : 0.f;

        float cv[8];
        float c2 = 0.f;
        #pragma unroll
        for (int nb = 0; nb < 8; ++nb) { cv[nb] = acc[nb][r] * m; c2 += cv[nb] * cv[nb]; }
        c2 += __shfl_xor(c2, 1);     // reduce across the quad's 16 lanes
        c2 += __shfl_xor(c2, 2);
        c2 += __shfl_xor(c2, 4);
        c2 += __shfl_xor(c2, 8);
        float nc = fmaxf(sqrtf(c2), EPSV);
        float sc = tanhf(nc) / nc;

        float xv[8];
        float s2 = 0.f;
        #pragma unroll
        for (int nb = 0; nb < 8; ++nb) {
            float t = fmaxf(cv[nb] * sc * m, 0.f) * m;   // expmap*m, relu, *m
            xv[nb] = t; s2 += t * t;
        }

        if (apply_logmap) {
            s2 += __shfl_xor(s2, 1);
            s2 += __shfl_xor(s2, 2);
            s2 += __shfl_xor(s2, 4);
            s2 += __shfl_xor(s2, 8);
            float nc2 = fminf(fmaxf(sqrtf(s2), EPSV), 1.f - EPSV);
            float sc2 = atanhf(nc2) / nc2;
            if (row < n) {
                _Float16* drow = dst_f16 + (size_t)row * DD + l15;
                #pragma unroll
                for (int nb = 0; nb < 8; ++nb) drow[nb * 16] = (_Float16)(xv[nb] * sc2);
            }
        } else {
            if (row < n) {
                float* drow = dst_f32 + (size_t)row * DD + l15;
                #pragma unroll
                for (int nb = 0; nb < 8; ++nb) drow[nb * 16] = xv[nb];
            }
        }
    }
}

extern "C" void kernel_launch(void* const* d_in, const int* in_sizes, int n_in,
                              void* d_out, int out_size, void* d_ws, size_t ws_size,
                              hipStream_t stream)
{
    const float* node_repr = (const float*)d_in[0];
    const int*   adj       = (const int*)  d_in[1];
    const float* weight    = (const float*)d_in[2];
    const float* mask      = (const float*)d_in[3];
    const float* W_pos     = (const float*)d_in[4];   // [L,128,128]
    const float* W_neg     = (const float*)d_in[5];

    const int n = in_sizes[0] / DD;                   // 50000

    _Float16* x16 = (_Float16*)d_ws;                  // n*128 f16
    _Float16* y16 = x16 + (size_t)n * DD;             // n*128 f16
    _Float16* WT  = y16 + (size_t)n * DD;             // 4 * 128*128 f16

    const int n4 = n * DD / 4;
    prep_x<<<(n4 + 255) / 256, 256, 0, stream>>>(node_repr, x16, n4);
    prep_w<<<4, 256, 0, stream>>>(W_pos, W_neg, WT);

    dim3 grid((n + TM - 1) / TM);
    // layer 0
    fused_layer<<<grid, 128, 0, stream>>>(x16, adj, weight, mask,
                                          WT + 0 * DD * DD, WT + 1 * DD * DD,
                                          nullptr, y16, n, 1);
    // layer 1
    fused_layer<<<grid, 128, 0, stream>>>(y16, adj, weight, mask,
                                          WT + 2 * DD * DD, WT + 3 * DD * DD,
                                          (float*)d_out, nullptr, n, 0);
}

// Round 5
// 204.664 us; speedup vs baseline: 1.5061x; 1.0283x over previous
//
#include <hip/hip_runtime.h>
#include <math.h>

#define DD 128          // embed dim
#define DEG 16          // neighbors
#define TM 16           // node tile per block (grid = 50000/16 = 3125 exactly)
#define LDST 136        // LDS row stride in f16
#define EPSV 1e-5f

typedef _Float16 half4_t __attribute__((ext_vector_type(4)));
typedef _Float16 half8_t __attribute__((ext_vector_type(8)));
typedef float    f32x4   __attribute__((ext_vector_type(4)));

// ---- prep: x16[s] = x[s] * mask[s]^2 (f16). Folding mask^2 here removes all
// mask gathers from the hot loop: msg[s] = m_s*((m_s*x[s])@W) = (m_s^2*x[s])@W.
__global__ void prep_x(const float* __restrict__ x, const float* __restrict__ mask,
                       _Float16* __restrict__ x16, int n4)
{
    int i = blockIdx.x * blockDim.x + threadIdx.x;
    if (i >= n4) return;
    float m = mask[i >> 5];            // 32 float4 groups per row
    float m2 = m * m;
    float4 v = ((const float4*)x)[i];
    half4_t h;
    h[0] = (_Float16)(v.x * m2); h[1] = (_Float16)(v.y * m2);
    h[2] = (_Float16)(v.z * m2); h[3] = (_Float16)(v.w * m2);
    ((half4_t*)x16)[i] = h;
}

// ---- prep: W [L][128][128] fp32 -> f16 TRANSPOSED WT[l][rel][n][k] ----
__global__ void prep_w(const float* __restrict__ Wp, const float* __restrict__ Wn,
                       _Float16* __restrict__ WT)
{
    const int l = blockIdx.x >> 1, rel = blockIdx.x & 1;
    const float* __restrict__ src = (rel ? Wn : Wp) + (size_t)l * DD * DD;
    _Float16* __restrict__ dst = WT + (size_t)blockIdx.x * DD * DD;
    for (int o = threadIdx.x; o < DD * DD; o += blockDim.x) {
        int nn = o >> 7, kk = o & 127;
        dst[o] = (_Float16)src[kk * DD + nn];
    }
}

// ---- one fused GNN layer ----
__global__ __launch_bounds__(256, 6) void fused_layer(
    const _Float16* __restrict__ src16,          // pre-scaled by mask^2
    const int*   __restrict__ adj, const float* __restrict__ wgt,
    const float* __restrict__ mask,
    const _Float16* __restrict__ WTp, const _Float16* __restrict__ WTn,
    float* __restrict__ dst_f32, _Float16* __restrict__ dst_f16,
    int n, int apply_logmap)
{
    __shared__ __align__(16) _Float16 aggP[TM][LDST];   // 4.25 KB
    __shared__ __align__(16) _Float16 aggN[TM][LDST];   // 4.25 KB
    __shared__ float partA[4][TM];                       // cross-wave norm partials
    __shared__ float partB[4][TM];

    const int row0   = blockIdx.x * TM;
    const int tid    = threadIdx.x;
    const int lane32 = tid & 31;
    const int hw2    = tid >> 5;       // half-wave 0..7

    // ---- phase 1: gather-aggregate; half-wave hw2 owns nodes 2*hw2, 2*hw2+1 ----
    #pragma unroll
    for (int i = 0; i < 2; ++i) {
        const int r    = hw2 * 2 + i;
        const int node = row0 + r;
        f32x4 aP = {0.f, 0.f, 0.f, 0.f};
        f32x4 aN = {0.f, 0.f, 0.f, 0.f};
        if (node < n) {
            const int*   __restrict__ arow = adj + (size_t)node * DEG;
            const float* __restrict__ wrow = wgt + (size_t)node * DEG;
            #pragma unroll
            for (int b = 0; b < 2; ++b) {      // 2 batches of 8 edges
                int4   i0 = ((const int4*)arow)[b * 2 + 0];
                int4   i1 = ((const int4*)arow)[b * 2 + 1];
                float4 w0 = ((const float4*)wrow)[b * 2 + 0];
                float4 w1 = ((const float4*)wrow)[b * 2 + 1];
                const int   idxs[8] = {i0.x, i0.y, i0.z, i0.w, i1.x, i1.y, i1.z, i1.w};
                const float ws[8]   = {w0.x, w0.y, w0.z, w0.w, w1.x, w1.y, w1.z, w1.w};
                half4_t v[8];                   // 8 independent gathers in flight
                #pragma unroll
                for (int j = 0; j < 8; ++j)
                    v[j] = *(const half4_t*)(src16 + (size_t)idxs[j] * DD + lane32 * 4);
                #pragma unroll
                for (int j = 0; j < 8; ++j) {
                    float wp = fmaxf(ws[j], 0.f);
                    float wn = fmaxf(-ws[j], 0.f);
                    float v0 = (float)v[j][0], v1 = (float)v[j][1];
                    float v2 = (float)v[j][2], v3 = (float)v[j][3];
                    aP[0] += wp * v0; aP[1] += wp * v1; aP[2] += wp * v2; aP[3] += wp * v3;
                    aN[0] += wn * v0; aN[1] += wn * v1; aN[2] += wn * v2; aN[3] += wn * v3;
                }
            }
        }
        half4_t hP, hN;
        hP[0] = (_Float16)aP[0]; hP[1] = (_Float16)aP[1];
        hP[2] = (_Float16)aP[2]; hP[3] = (_Float16)aP[3];
        hN[0] = (_Float16)aN[0]; hN[1] = (_Float16)aN[1];
        hN[2] = (_Float16)aN[2]; hN[3] = (_Float16)aN[3];
        *(half4_t*)&aggP[r][lane32 * 4] = hP;
        *(half4_t*)&aggN[r][lane32 * 4] = hN;
    }
    __syncthreads();

    // ---- phase 2: MFMA. 4 waves split the 8 n-blocks (2 each); rows shared ----
    const int wv2  = tid >> 6;       // wave 0..3
    const int l64  = tid & 63;
    const int l15  = l64 & 15;
    const int quad = l64 >> 4;

    half8_t aPf[4], aNf[4];          // A[m=l15][k=kb*32+quad*8+j]
    #pragma unroll
    for (int kb = 0; kb < 4; ++kb) {
        aPf[kb] = *(const half8_t*)&aggP[l15][kb * 32 + quad * 8];
        aNf[kb] = *(const half8_t*)&aggN[l15][kb * 32 + quad * 8];
    }

    f32x4 acc[2];
    acc[0] = (f32x4){0.f, 0.f, 0.f, 0.f};
    acc[1] = (f32x4){0.f, 0.f, 0.f, 0.f};
    #pragma unroll
    for (int t = 0; t < 2; ++t) {
        const int nb = wv2 * 2 + t;
        const _Float16* bp = WTp + (size_t)(nb * 16 + l15) * DD + quad * 8;
        const _Float16* bn = WTn + (size_t)(nb * 16 + l15) * DD + quad * 8;
        #pragma unroll
        for (int kb = 0; kb < 4; ++kb) {
            acc[t] = __builtin_amdgcn_mfma_f32_16x16x32_f16(
                aPf[kb], *(const half8_t*)(bp + kb * 32), acc[t], 0, 0, 0);
            acc[t] = __builtin_amdgcn_mfma_f32_16x16x32_f16(
                aNf[kb], *(const half8_t*)(bn + kb * 32), acc[t], 0, 0, 0);
        }
    }

    // ---- phase 3: epilogue. C/D: row=quad*4+r, cols wv2*32 + {l15, 16+l15} ----
    float cv0[4], cv1[4], mr[4];
    #pragma unroll
    for (int r = 0; r < 4; ++r) {
        const int rl  = quad * 4 + r;
        const int row = row0 + rl;
        float m = (row < n) ? mask[row] : 0.f;
        mr[r] = m;
        float c0 = acc[0][r] * m, c1 = acc[1][r] * m;
        cv0[r] = c0; cv1[r] = c1;
        float p = c0 * c0 + c1 * c1;
        p += __shfl_xor(p, 1); p += __shfl_xor(p, 2);
        p += __shfl_xor(p, 4); p += __shfl_xor(p, 8);   // within 16-lane quad group
        if (l15 == 0) partA[wv2][rl] = p;
    }
    __syncthreads();

    float x0[4], x1[4];
    #pragma unroll
    for (int r = 0; r < 4; ++r) {
        const int rl = quad * 4 + r;
        float c2 = partA[0][rl] + partA[1][rl] + partA[2][rl] + partA[3][rl];
        float nc = fmaxf(sqrtf(c2), EPSV);
        float sc = tanhf(nc) / nc;
        float m  = mr[r];
        float t0 = fmaxf(cv0[r] * sc * m, 0.f) * m;      // expmap*m, relu, *m
        float t1 = fmaxf(cv1[r] * sc * m, 0.f) * m;
        x0[r] = t0; x1[r] = t1;
        if (apply_logmap) {                               // uniform branch
            float p = t0 * t0 + t1 * t1;
            p += __shfl_xor(p, 1); p += __shfl_xor(p, 2);
            p += __shfl_xor(p, 4); p += __shfl_xor(p, 8);
            if (l15 == 0) partB[wv2][rl] = p;
        }
    }

    if (apply_logmap) {
        __syncthreads();
        #pragma unroll
        for (int r = 0; r < 4; ++r) {
            const int rl  = quad * 4 + r;
            const int row = row0 + rl;
            if (row >= n) continue;
            float s2  = partB[0][rl] + partB[1][rl] + partB[2][rl] + partB[3][rl];
            float nc2 = fminf(fmaxf(sqrtf(s2), EPSV), 1.f - EPSV);
            // store logmap(x)*mask^2 so the next layer's gather needs no mask
            float f = (atanhf(nc2) / nc2) * mr[r] * mr[r];
            _Float16* drow = dst_f16 + (size_t)row * DD + wv2 * 32 + l15;
            drow[0]  = (_Float16)(x0[r] * f);
            drow[16] = (_Float16)(x1[r] * f);
        }
    } else {
        #pragma unroll
        for (int r = 0; r < 4; ++r) {
            const int rl  = quad * 4 + r;
            const int row = row0 + rl;
            if (row >= n) continue;
            float* drow = dst_f32 + (size_t)row * DD + wv2 * 32 + l15;
            drow[0]  = x0[r];
            drow[16] = x1[r];
        }
    }
}

extern "C" void kernel_launch(void* const* d_in, const int* in_sizes, int n_in,
                              void* d_out, int out_size, void* d_ws, size_t ws_size,
                              hipStream_t stream)
{
    const float* node_repr = (const float*)d_in[0];
    const int*   adj       = (const int*)  d_in[1];
    const float* weight    = (const float*)d_in[2];
    const float* mask      = (const float*)d_in[3];
    const float* W_pos     = (const float*)d_in[4];   // [L,128,128]
    const float* W_neg     = (const float*)d_in[5];

    const int n = in_sizes[0] / DD;                   // 50000

    _Float16* x16 = (_Float16*)d_ws;                  // n*128 f16
    _Float16* y16 = x16 + (size_t)n * DD;             // n*128 f16
    _Float16* WT  = y16 + (size_t)n * DD;             // 4 * 128*128 f16

    const int n4 = n * DD / 4;
    prep_x<<<(n4 + 255) / 256, 256, 0, stream>>>(node_repr, mask, x16, n4);
    prep_w<<<4, 256, 0, stream>>>(W_pos, W_neg, WT);

    dim3 grid((n + TM - 1) / TM);
    // layer 0
    fused_layer<<<grid, 256, 0, stream>>>(x16, adj, weight, mask,
                                          WT + 0 * DD * DD, WT + 1 * DD * DD,
                                          nullptr, y16, n, 1);
    // layer 1
    fused_layer<<<grid, 256, 0, stream>>>(y16, adj, weight, mask,
                                          WT + 2 * DD * DD, WT + 3 * DD * DD,
                                          (float*)d_out, nullptr, n, 0);
}

// Round 6
// 188.089 us; speedup vs baseline: 1.6388x; 1.0881x over previous
//
#include <hip/hip_runtime.h>
#include <math.h>

#define DD 128          // embed dim
#define DEG 16          // neighbors
#define TM 16           // node tile per block (grid = 50000/16 = 3125 exactly)
#define LDST 136        // LDS row stride in f16
#define EPSV 1e-5f

typedef _Float16 half4_t __attribute__((ext_vector_type(4)));
typedef _Float16 half8_t __attribute__((ext_vector_type(8)));
typedef float    f32x4   __attribute__((ext_vector_type(4)));

// ---- prep (single kernel): x16[s] = x[s]*mask[s]^2 (f16), plus W->f16 transpose.
// Folding mask^2 removes all mask gathers: msg[s] = m_s*((m_s*x[s])@W) = (m_s^2*x[s])@W.
__global__ void prep(const float* __restrict__ x, const float* __restrict__ mask,
                     _Float16* __restrict__ x16, int n4, int xb,
                     const float* __restrict__ Wp, const float* __restrict__ Wn,
                     _Float16* __restrict__ WT)
{
    if ((int)blockIdx.x < xb) {
        int i = blockIdx.x * blockDim.x + threadIdx.x;
        if (i >= n4) return;
        float m = mask[i >> 5];            // 32 half4 groups per row
        float m2 = m * m;
        float4 v = ((const float4*)x)[i];
        half4_t h;
        h[0] = (_Float16)(v.x * m2); h[1] = (_Float16)(v.y * m2);
        h[2] = (_Float16)(v.z * m2); h[3] = (_Float16)(v.w * m2);
        ((half4_t*)x16)[i] = h;
    } else {
        // 32 blocks: mat = (l,rel) in WT order [l0p, l0n, l1p, l1n], 8 chunks each
        int bid   = blockIdx.x - xb;
        int mat   = bid >> 3;              // 0..3
        int chunk = bid & 7;
        int l = mat >> 1, rel = mat & 1;
        const float* __restrict__ src = (rel ? Wn : Wp) + (size_t)l * DD * DD;
        _Float16* __restrict__ dst = WT + (size_t)mat * DD * DD;
        for (int o = chunk * 2048 + threadIdx.x; o < chunk * 2048 + 2048; o += 256) {
            int nn = o >> 7, kk = o & 127;
            dst[o] = (_Float16)src[kk * DD + nn];   // WT[n][k] (transposed)
        }
    }
}

// ---- one fused GNN layer ----
__global__ __launch_bounds__(256, 4) void fused_layer(
    const _Float16* __restrict__ src16,          // pre-scaled by mask^2
    const int*   __restrict__ adj, const float* __restrict__ wgt,
    const float* __restrict__ mask,
    const _Float16* __restrict__ WTp, const _Float16* __restrict__ WTn,
    float* __restrict__ dst_f32, _Float16* __restrict__ dst_f16,
    int n, int apply_logmap)
{
    __shared__ __align__(16) _Float16 aggP[TM][LDST];   // 4.25 KB
    __shared__ __align__(16) _Float16 aggN[TM][LDST];   // 4.25 KB
    __shared__ float partA[4][TM];                       // cross-wave norm partials
    __shared__ float partB[4][TM];

    const int row0 = blockIdx.x * TM;
    const int tid  = threadIdx.x;
    const int qw   = tid >> 4;         // quarter-wave 0..15 -> owns node row qw
    const int l16  = tid & 15;         // covers cols [8*l16, 8*l16+8)

    // ---- phase 1: gather-aggregate; ALL 16 edges in flight (16B/lane loads) ----
    float aP[8] = {0.f,0.f,0.f,0.f,0.f,0.f,0.f,0.f};
    float aN[8] = {0.f,0.f,0.f,0.f,0.f,0.f,0.f,0.f};
    const int node = row0 + qw;
    if (node < n) {
        const int*   __restrict__ arow = adj + (size_t)node * DEG;
        const float* __restrict__ wrow = wgt + (size_t)node * DEG;
        int   idxs[16];
        float ws[16];
        #pragma unroll
        for (int b = 0; b < 4; ++b) {
            int4   ia = ((const int4*)arow)[b];
            float4 wa = ((const float4*)wrow)[b];
            idxs[b*4+0] = ia.x; idxs[b*4+1] = ia.y; idxs[b*4+2] = ia.z; idxs[b*4+3] = ia.w;
            ws[b*4+0] = wa.x; ws[b*4+1] = wa.y; ws[b*4+2] = wa.z; ws[b*4+3] = wa.w;
        }
        half8_t v[16];                  // 16 independent 16B gathers in flight
        #pragma unroll
        for (int j = 0; j < 16; ++j)
            v[j] = *(const half8_t*)(src16 + (size_t)idxs[j] * DD + l16 * 8);
        #pragma unroll
        for (int j = 0; j < 16; ++j) {
            float wp = fmaxf(ws[j], 0.f);
            float wn = fmaxf(-ws[j], 0.f);
            #pragma unroll
            for (int c = 0; c < 8; ++c) {
                float f = (float)v[j][c];
                aP[c] += wp * f;
                aN[c] += wn * f;
            }
        }
    }
    half8_t hP, hN;
    #pragma unroll
    for (int c = 0; c < 8; ++c) { hP[c] = (_Float16)aP[c]; hN[c] = (_Float16)aN[c]; }
    *(half8_t*)&aggP[qw][l16 * 8] = hP;
    *(half8_t*)&aggN[qw][l16 * 8] = hN;
    __syncthreads();

    // ---- phase 2: MFMA. 4 waves split the 8 n-blocks (2 each); rows shared ----
    const int wv2  = tid >> 6;       // wave 0..3
    const int l64  = tid & 63;
    const int l15  = l64 & 15;
    const int quad = l64 >> 4;

    half8_t aPf[4], aNf[4];          // A[m=l15][k=kb*32+quad*8+j]
    #pragma unroll
    for (int kb = 0; kb < 4; ++kb) {
        aPf[kb] = *(const half8_t*)&aggP[l15][kb * 32 + quad * 8];
        aNf[kb] = *(const half8_t*)&aggN[l15][kb * 32 + quad * 8];
    }

    f32x4 acc[2];
    acc[0] = (f32x4){0.f, 0.f, 0.f, 0.f};
    acc[1] = (f32x4){0.f, 0.f, 0.f, 0.f};
    #pragma unroll
    for (int t = 0; t < 2; ++t) {
        const int nb = wv2 * 2 + t;
        const _Float16* bp = WTp + (size_t)(nb * 16 + l15) * DD + quad * 8;
        const _Float16* bn = WTn + (size_t)(nb * 16 + l15) * DD + quad * 8;
        #pragma unroll
        for (int kb = 0; kb < 4; ++kb) {
            acc[t] = __builtin_amdgcn_mfma_f32_16x16x32_f16(
                aPf[kb], *(const half8_t*)(bp + kb * 32), acc[t], 0, 0, 0);
            acc[t] = __builtin_amdgcn_mfma_f32_16x16x32_f16(
                aNf[kb], *(const half8_t*)(bn + kb * 32), acc[t], 0, 0, 0);
        }
    }

    // ---- phase 3: epilogue. C/D: row=quad*4+r, cols wv2*32 + {l15, 16+l15} ----
    float cv0[4], cv1[4], mr[4];
    #pragma unroll
    for (int r = 0; r < 4; ++r) {
        const int rl  = quad * 4 + r;
        const int row = row0 + rl;
        float m = (row < n) ? mask[row] : 0.f;
        mr[r] = m;
        float c0 = acc[0][r] * m, c1 = acc[1][r] * m;
        cv0[r] = c0; cv1[r] = c1;
        float p = c0 * c0 + c1 * c1;
        p += __shfl_xor(p, 1); p += __shfl_xor(p, 2);
        p += __shfl_xor(p, 4); p += __shfl_xor(p, 8);   // within 16-lane group
        if (l15 == 0) partA[wv2][rl] = p;
    }
    __syncthreads();

    float x0[4], x1[4];
    #pragma unroll
    for (int r = 0; r < 4; ++r) {
        const int rl = quad * 4 + r;
        float c2 = partA[0][rl] + partA[1][rl] + partA[2][rl] + partA[3][rl];
        float nc = fmaxf(sqrtf(c2), EPSV);
        float sc = tanhf(nc) / nc;
        float m  = mr[r];
        float t0 = fmaxf(cv0[r] * sc * m, 0.f) * m;      // expmap*m, relu, *m
        float t1 = fmaxf(cv1[r] * sc * m, 0.f) * m;
        x0[r] = t0; x1[r] = t1;
        if (apply_logmap) {                               // uniform branch
            float p = t0 * t0 + t1 * t1;
            p += __shfl_xor(p, 1); p += __shfl_xor(p, 2);
            p += __shfl_xor(p, 4); p += __shfl_xor(p, 8);
            if (l15 == 0) partB[wv2][rl] = p;
        }
    }

    if (apply_logmap) {
        __syncthreads();
        #pragma unroll
        for (int r = 0; r < 4; ++r) {
            const int rl  = quad * 4 + r;
            const int row = row0 + rl;
            if (row >= n) continue;
            float s2  = partB[0][rl] + partB[1][rl] + partB[2][rl] + partB[3][rl];
            float nc2 = fminf(fmaxf(sqrtf(s2), EPSV), 1.f - EPSV);
            // store logmap(x)*mask^2 so the next layer's gather needs no mask
            float f = (atanhf(nc2) / nc2) * mr[r] * mr[r];
            _Float16* drow = dst_f16 + (size_t)row * DD + wv2 * 32 + l15;
            drow[0]  = (_Float16)(x0[r] * f);
            drow[16] = (_Float16)(x1[r] * f);
        }
    } else {
        #pragma unroll
        for (int r = 0; r < 4; ++r) {
            const int rl  = quad * 4 + r;
            const int row = row0 + rl;
            if (row >= n) continue;
            float* drow = dst_f32 + (size_t)row * DD + wv2 * 32 + l15;
            drow[0]  = x0[r];
            drow[16] = x1[r];
        }
    }
}

extern "C" void kernel_launch(void* const* d_in, const int* in_sizes, int n_in,
                              void* d_out, int out_size, void* d_ws, size_t ws_size,
                              hipStream_t stream)
{
    const float* node_repr = (const float*)d_in[0];
    const int*   adj       = (const int*)  d_in[1];
    const float* weight    = (const float*)d_in[2];
    const float* mask      = (const float*)d_in[3];
    const float* W_pos     = (const float*)d_in[4];   // [L,128,128]
    const float* W_neg     = (const float*)d_in[5];

    const int n = in_sizes[0] / DD;                   // 50000

    _Float16* x16 = (_Float16*)d_ws;                  // n*128 f16
    _Float16* y16 = x16 + (size_t)n * DD;             // n*128 f16
    _Float16* WT  = y16 + (size_t)n * DD;             // 4 * 128*128 f16

    const int n4 = n * DD / 4;
    const int xb = (n4 + 255) / 256;
    prep<<<xb + 32, 256, 0, stream>>>(node_repr, mask, x16, n4, xb,
                                      W_pos, W_neg, WT);

    dim3 grid((n + TM - 1) / TM);
    // layer 0
    fused_layer<<<grid, 256, 0, stream>>>(x16, adj, weight, mask,
                                          WT + 0 * DD * DD, WT + 1 * DD * DD,
                                          nullptr, y16, n, 1);
    // layer 1
    fused_layer<<<grid, 256, 0, stream>>>(y16, adj, weight, mask,
                                          WT + 2 * DD * DD, WT + 3 * DD * DD,
                                          (float*)d_out, nullptr, n, 0);
}